// Round 12
// baseline (793.455 us; speedup 1.0000x reference)
//
#include <hip/hip_runtime.h>
#include <hip/hip_fp16.h>
#include <math.h>

#define N_NODES 20000
#define N_EDGES 320000
#define F_IN    128
#define E_IN    64
#define HID     64
#define NH      4
#define CH      64
#define HC      256   // NH*CH
#define L_LAYERS 4
#define OUT_DIM 32
#define WCOLS   1088  // packed col space: 512 qqw | 512 kv | 64 skip

typedef _Float16 half8 __attribute__((ext_vector_type(8)));
typedef _Float16 half4 __attribute__((ext_vector_type(4)));
typedef float f32x4 __attribute__((ext_vector_type(4)));

// ---------------- CSR build ----------------
__global__ __launch_bounds__(256) void hist_dst(const int* __restrict__ dst,
                                                int* __restrict__ hist) {
    int e = blockIdx.x * 256 + threadIdx.x;
    if (e < N_EDGES) atomicAdd(&hist[dst[e]], 1);
}

// one block, 1024 threads: degree-descending rank + CSR row pointers
__global__ __launch_bounds__(1024) void build_order(const int* __restrict__ hist,
                                                    int* __restrict__ node_order,
                                                    int* __restrict__ rank_of,
                                                    int* __restrict__ deg_rank,
                                                    int* __restrict__ new_rp,
                                                    int* __restrict__ cursor2) {
    __shared__ int bins[256];
    __shared__ int curb[256];
    __shared__ int sums[1024];
    int t = threadIdx.x;
    if (t < 256) bins[t] = 0;
    __syncthreads();
    for (int n = t; n < N_NODES; n += 1024) {
        int d = hist[n]; if (d > 255) d = 255;
        atomicAdd(&bins[d], 1);
    }
    __syncthreads();
    if (t < 256) {
        int acc = 0;
        for (int b = t + 1; b < 256; b++) acc += bins[b];
        curb[t] = acc;
    }
    __syncthreads();
    for (int n = t; n < N_NODES; n += 1024) {
        int d = hist[n];
        int b = d > 255 ? 255 : d;
        int r = atomicAdd(&curb[b], 1);
        node_order[r] = n;
        rank_of[n] = r;
        deg_rank[r] = d;
    }
    __syncthreads();
    const int CHUNK = 20;  // 1024*20 >= 20000
    int base = t * CHUNK;
    int local[CHUNK];
    int s = 0;
    for (int i = 0; i < CHUNK; i++) {
        int idx = base + i;
        int vv = (idx < N_NODES) ? deg_rank[idx] : 0;
        local[i] = s;
        s += vv;
    }
    sums[t] = s;
    __syncthreads();
    for (int off = 1; off < 1024; off <<= 1) {
        int v = (t >= off) ? sums[t - off] : 0;
        __syncthreads();
        sums[t] += v;
        __syncthreads();
    }
    int excl = (t == 0) ? 0 : sums[t - 1];
    for (int i = 0; i < CHUNK; i++) {
        int idx = base + i;
        if (idx < N_NODES) {
            int p = excl + local[i];
            new_rp[idx] = p;
            cursor2[idx] = p;
        }
    }
    if (t == 1023) new_rp[N_NODES] = sums[1023];
}

// phase A: positions only
__global__ __launch_bounds__(256) void compute_pos(const int* __restrict__ src,
                                                   const int* __restrict__ dst,
                                                   const int* __restrict__ rank_of,
                                                   int* __restrict__ cursor2,
                                                   int* __restrict__ eid_of,
                                                   int* __restrict__ srcrank_perm) {
    int e = blockIdx.x * 256 + threadIdx.x;
    if (e >= N_EDGES) return;
    int r = rank_of[dst[e]];
    int pos = atomicAdd(&cursor2[r], 1);
    eid_of[pos] = e;
    srcrank_perm[pos] = rank_of[src[e]];
}

// phase B: gather-form attr permute + fp16 convert
__global__ __launch_bounds__(256) void permute_attr(const int* __restrict__ eid_of,
                                                    const float* __restrict__ eattr,
                                                    __half* __restrict__ attr_p) {
    int t = threadIdx.x;
    int wave = t >> 6, lane = t & 63;
    int p = blockIdx.x * 16 + wave * 4 + (lane >> 4);
    if (p >= N_EDGES) return;
    int e = eid_of[p];
    int qi = (lane & 15) * 4;
    float4 a = *(const float4*)(eattr + (size_t)e * E_IN + qi);
    __half2 h0 = __floats2half2_rn(a.x, a.y);
    __half2 h1 = __floats2half2_rn(a.z, a.w);
    uint2 packed;
    packed.x = *(unsigned int*)&h0;
    packed.y = *(unsigned int*)&h1;
    *(uint2*)(attr_p + (size_t)p * E_IN + qi) = packed;
}

// ---------------- per-layer constants ----------------
// fused: Wqe (LDS) -> Wqe2 / bqe2 / wqb / bqb
__global__ __launch_bounds__(256) void make_wqeA(const float* __restrict__ Wq,
                                                 const float* __restrict__ bq,
                                                 const float* __restrict__ We,
                                                 const float* __restrict__ eW,
                                                 const float* __restrict__ eb,
                                                 float* __restrict__ Wqe2,
                                                 float* __restrict__ bqe2,
                                                 float* __restrict__ wqb,
                                                 float* __restrict__ bqb) {
    int l = blockIdx.x / HID, i = blockIdx.x % HID;
    int t = threadIdx.x;
    int h = t >> 6, j = t & 63;
    __shared__ float wrow[256];
    __shared__ float brow[256];
    const float* WqL = Wq + (size_t)l * HID * HC;
    const float* WeL = We + (size_t)l * HID * HC;
    float acc = 0.f;
    for (int c = 0; c < CH; c++)
        acc += WqL[i * HC + h * CH + c] * WeL[j * HC + h * CH + c];
    wrow[t] = acc;
    if (i == 0) {
        const float* bqL = bq + l * HC;
        float ab = 0.f;
        for (int c = 0; c < CH; c++)
            ab += bqL[h * CH + c] * WeL[j * HC + h * CH + c];
        brow[t] = ab;
    }
    __syncthreads();
    int h2 = t >> 6, m = t & 63;
    float a2 = 0.f;
    for (int jj = 0; jj < HID; jj++) a2 += wrow[h2 * 64 + jj] * eW[m * HID + jj];
    Wqe2[(size_t)l * HID * HC + i * HC + t] = a2;
    if (m == 0) {
        float aw = 0.f;
        for (int jj = 0; jj < HID; jj++) aw += wrow[h2 * 64 + jj] * eb[jj];
        wqb[l * HID * NH + i * NH + h2] = aw;
    }
    if (i == 0) {
        float ab2 = 0.f;
        for (int jj = 0; jj < HID; jj++) ab2 += brow[h2 * 64 + jj] * eW[m * HID + jj];
        bqe2[l * HC + t] = ab2;
        if (m == 0) {
            float bb = 0.f;
            for (int jj = 0; jj < HID; jj++) bb += brow[h2 * 64 + jj] * eb[jj];
            bqb[l * NH + h2] = bb;
        }
    }
}

// Wcat16[l][c(64)][k=h*64+m (256)] = f16( WeE[m][h*64+c] );  beE fp32
__global__ __launch_bounds__(256) void make_wcat(const float* __restrict__ eW,
                                                 const float* __restrict__ eb,
                                                 const float* __restrict__ We,
                                                 _Float16* __restrict__ Wcat16,
                                                 float* __restrict__ beE) {
    int l = blockIdx.x / 64, c = blockIdx.x % 64;
    int t = threadIdx.x;
    __shared__ float sh[4][64];    // sh[h][j] = We[j][h*64+c]
    {
        int j = t & 63, h = t >> 6;
        sh[h][j] = We[(size_t)l * HID * HC + j * HC + h * 64 + c];
    }
    __syncthreads();
    int h = t >> 6, m = t & 63;
    float acc = 0.f;
    for (int j = 0; j < HID; j++) acc += eW[m * HID + j] * sh[h][j];
    Wcat16[((size_t)l * 64 + c) * 256 + t] = (_Float16)acc;
    if (t < 4) {
        float a = 0.f;
        for (int j = 0; j < HID; j++) a += eb[j] * sh[t][j];
        beE[l * HC + t * 64 + c] = a;
    }
}

// W16T: columns pre-permuted into the PACKED output order (see round 9)
__global__ __launch_bounds__(256) void make_w16(
        const float* __restrict__ Wq, const float* __restrict__ Wk,
        const float* __restrict__ Wv, const float* __restrict__ Wqe2,
        const float* __restrict__ Wsk,
        const float* __restrict__ bq, const float* __restrict__ bk,
        const float* __restrict__ bv, const float* __restrict__ bqe2,
        const float* __restrict__ bsk,
        _Float16* __restrict__ W16T, float* __restrict__ biasc) {
    int l = blockIdx.x / 272;
    int cg = blockIdx.x % 272;
    int col = cg * 4 + (threadIdx.x >> 6);
    int i = threadIdx.x & 63;
    float w, b;
    if (col < 512) {
        int c = (col >> 3) * 4 + (col & 3);
        if ((col >> 2) & 1) { w = Wqe2[(size_t)l*HID*HC + i*HC + c]; b = bqe2[l*HC + c]; }
        else                { w = Wq[(size_t)l*HID*HC + i*HC + c];   b = bq[l*HC + c]; }
    } else if (col < 1024) {
        int cc = col - 512;
        int c = (cc >> 3) * 4 + (cc & 3);
        if ((cc >> 2) & 1) { w = Wv[(size_t)l*HID*HC + i*HC + c]; b = bv[l*HC + c]; }
        else               { w = Wk[(size_t)l*HID*HC + i*HC + c]; b = bk[l*HC + c]; }
    } else {
        int c = col - 1024;
        w = Wsk[(size_t)l*HID*HID + i*HID + c];  b = bsk[l*HID + c];
    }
    W16T[((size_t)l * WCOLS + col) * 64 + i] = (_Float16)w;
    if (i == 0) biasc[l * WCOLS + col] = b;
}

// W0T[col][i] = f16 node_W[i][col]  (64 cols, K=128); b0 fp32
__global__ __launch_bounds__(256) void make_w0(const float* __restrict__ nW,
                                               const float* __restrict__ nb,
                                               _Float16* __restrict__ W0T,
                                               float* __restrict__ b0) {
    int col = blockIdx.x * 2 + (threadIdx.x >> 7);
    int i = threadIdx.x & 127;
    W0T[col * F_IN + i] = (_Float16)nW[i * HID + col];
    if (i == 0) b0[col] = nb[col];
}

// ---------------- layer-0: fused node-encoder + pre-pass (32 nodes/block) ----------------
__global__ __launch_bounds__(256) void node_pre0(const float* __restrict__ x,
        const int* __restrict__ node_order,
        const _Float16* __restrict__ W0T, const float* __restrict__ b0,
        const _Float16* __restrict__ W16T, const float* __restrict__ biasc,
        const float* __restrict__ wqb, const float* __restrict__ bqb,
        _Float16* __restrict__ qqw, _Float16* __restrict__ kv,
        float* __restrict__ skip, float* __restrict__ qb) {
    int t = threadIdx.x;
    int wave = t >> 6, lane = t & 63;
    int quad = lane >> 4, mrow = lane & 15;
    int base = blockIdx.x * 32;
    __shared__ _Float16 xs[32][136];
    __shared__ _Float16 zs[32][72];
    __shared__ int nord[32];
    if (t < 32) nord[t] = node_order[base + t];
    __syncthreads();
    for (int it = 0; it < 4; it++) {
        int idx = it * 256 + t;          // 1024 float4 = 32 rows x 32
        int m = idx >> 5, c4 = idx & 31;
        float4 a = *(const float4*)(x + (size_t)nord[m] * F_IN + c4 * 4);
        _Float16* d = &xs[m][c4 * 4];
        d[0] = (_Float16)a.x; d[1] = (_Float16)a.y;
        d[2] = (_Float16)a.z; d[3] = (_Float16)a.w;
    }
    __syncthreads();
    // h0 = x @ node_W + node_b, SWAPPED: D[wcol][node] -> 8B LDS stores
    {
        int colb = wave * 16;
        const _Float16* w0row = W0T + (size_t)(colb + mrow) * F_IN;
        f32x4 acc0 = {0.f, 0.f, 0.f, 0.f};
        f32x4 acc1 = {0.f, 0.f, 0.f, 0.f};
#pragma unroll
        for (int kk = 0; kk < 4; kk++) {
            half8 wfrag = *(const half8*)(w0row + kk * 32 + quad * 8);
            half8 xf0 = *(const half8*)&xs[mrow][kk * 32 + quad * 8];
            half8 xf1 = *(const half8*)&xs[16 + mrow][kk * 32 + quad * 8];
            acc0 = __builtin_amdgcn_mfma_f32_16x16x32_f16(wfrag, xf0, acc0, 0, 0, 0);
            acc1 = __builtin_amdgcn_mfma_f32_16x16x32_f16(wfrag, xf1, acc1, 0, 0, 0);
        }
        float4 bb = *(const float4*)(b0 + colb + quad * 4);
        half4 h0v = {(_Float16)(acc0[0] + bb.x), (_Float16)(acc0[1] + bb.y),
                     (_Float16)(acc0[2] + bb.z), (_Float16)(acc0[3] + bb.w)};
        half4 h1v = {(_Float16)(acc1[0] + bb.x), (_Float16)(acc1[1] + bb.y),
                     (_Float16)(acc1[2] + bb.z), (_Float16)(acc1[3] + bb.w)};
        *(half4*)&zs[mrow][colb + quad * 4] = h0v;
        *(half4*)&zs[16 + mrow][colb + quad * 4] = h1v;
    }
    __syncthreads();
    // qb: 128 (m,h4) pairs x 2 threads
    {
        int p = t >> 1, s4 = t & 1;
        int m = p >> 2, h4 = p & 3;
        float a = 0.f;
        for (int i = s4 * 32; i < s4 * 32 + 32; i++)
            a += (float)zs[m][i] * wqb[i * NH + h4];
        a += __shfl_xor(a, 1);
        if (s4 == 0) qb[(base + m) * NH + h4] = a + bqb[h4];
    }
    half8 a00 = *(const half8*)&zs[mrow][quad * 8];
    half8 a01 = *(const half8*)&zs[mrow][32 + quad * 8];
    half8 a10 = *(const half8*)&zs[16 + mrow][quad * 8];
    half8 a11 = *(const half8*)&zs[16 + mrow][32 + quad * 8];
    int colwave = wave * 272;
    for (int tile = 0; tile < 17; tile++) {
        int colb = colwave + tile * 16;
        const _Float16* wrow = W16T + (size_t)(colb + mrow) * 64;
        half8 b0f = *(const half8*)(wrow + quad * 8);
        half8 b1f = *(const half8*)(wrow + 32 + quad * 8);
        f32x4 acc0 = {0.f, 0.f, 0.f, 0.f};
        f32x4 acc1 = {0.f, 0.f, 0.f, 0.f};
        acc0 = __builtin_amdgcn_mfma_f32_16x16x32_f16(b0f, a00, acc0, 0, 0, 0);
        acc0 = __builtin_amdgcn_mfma_f32_16x16x32_f16(b1f, a01, acc0, 0, 0, 0);
        acc1 = __builtin_amdgcn_mfma_f32_16x16x32_f16(b0f, a10, acc1, 0, 0, 0);
        acc1 = __builtin_amdgcn_mfma_f32_16x16x32_f16(b1f, a11, acc1, 0, 0, 0);
        float4 bi4 = *(const float4*)(biasc + colb + quad * 4);
        int wc = colb + quad * 4;
        int ra = base + mrow, rb = ra + 16;
        float v00 = acc0[0] + bi4.x, v01 = acc0[1] + bi4.y;
        float v02 = acc0[2] + bi4.z, v03 = acc0[3] + bi4.w;
        float v10 = acc1[0] + bi4.x, v11 = acc1[1] + bi4.y;
        float v12 = acc1[2] + bi4.z, v13 = acc1[3] + bi4.w;
        if (colb >= 1024) {
            *(float4*)(skip + ra * HID + (wc - 1024)) = make_float4(v00, v01, v02, v03);
            *(float4*)(skip + rb * HID + (wc - 1024)) = make_float4(v10, v11, v12, v13);
        } else {
            half4 p0 = {(_Float16)v00, (_Float16)v01, (_Float16)v02, (_Float16)v03};
            half4 p1 = {(_Float16)v10, (_Float16)v11, (_Float16)v12, (_Float16)v13};
            if (colb < 512) {
                *(half4*)(qqw + (size_t)ra * 512 + wc) = p0;
                *(half4*)(qqw + (size_t)rb * 512 + wc) = p1;
            } else {
                *(half4*)(kv + (size_t)ra * 512 + (wc - 512)) = p0;
                *(half4*)(kv + (size_t)rb * 512 + (wc - 512)) = p1;
            }
        }
    }
}

// ---------------- FUSED per-layer step: gather + post + LN + pre(next) ----------------
// 512 threads = 8 waves; 8 ranks/block, ONE wave per rank (full gather MLP).
// Numerators stay in LDS. kv double-buffered across layers.
__global__ __launch_bounds__(512) void layer_step(
        const int* __restrict__ new_rp,
        const int* __restrict__ srcrank_perm,
        const __half* __restrict__ attr_p,
        const __half* __restrict__ kv_in,
        _Float16* __restrict__ qqw,
        float* __restrict__ qb,
        float* __restrict__ skip,
        float* __restrict__ hg,               // rank-indexed h
        const _Float16* __restrict__ Wcat16, const float* __restrict__ beE,
        int add_res,
        const _Float16* __restrict__ W16T, const float* __restrict__ biasc,
        const float* __restrict__ wqb, const float* __restrict__ bqb,
        const float* __restrict__ g, const float* __restrict__ be,
        _Float16* __restrict__ kv_out,
        int last,
        const int* __restrict__ node_order,
        const float* __restrict__ linW, const float* __restrict__ linb,
        float* __restrict__ out) {
    int t = threadIdx.x;
    int wave = t >> 6, lane = t & 63;
    int quad = lane >> 4, mrow = lane & 15;
    int head = quad;
    int base = blockIdx.x * 8;
    __shared__ _Float16 ea16[16][264];   // rows 8..15 never written (garbage ok)
    __shared__ _Float16 nvs[8][264];     // scaled numv
    __shared__ float hnew[8][64];
    __shared__ _Float16 zs[16][72];      // rows 8..15 garbage ok
    __shared__ float bsh[256];
    __shared__ float ffs[32];            // [m*4+h] = den/(den+eps)
    __shared__ int nord[8];
    if (t < 256) bsh[t] = beE[t];
    if (t < 8) nord[t] = node_order[base + t];
    int qi = mrow * 4;
    // ---- phase 1: gather — wave `wave` owns rank base+wave ----
    {
        int m = wave;
        int r = base + m;
        int e0 = new_rp[r], e1 = new_rp[r + 1];
        uint4 qr = *(const uint4*)(qqw + (size_t)r * 512 + lane * 8);
        float2 q01 = __half22float2(*(__half2*)&qr.x);
        float2 q23 = __half22float2(*(__half2*)&qr.y);
        float2 w01 = __half22float2(*(__half2*)&qr.z);
        float2 w23 = __half22float2(*(__half2*)&qr.w);
        float qbh = qb[r * NH + head];
        float4 nv = make_float4(0.f, 0.f, 0.f, 0.f);
        float4 ne = make_float4(0.f, 0.f, 0.f, 0.f);
        float dsum = 0.f;
#pragma unroll 2
        for (int e = e0; e < e1; e++) {
            int s_ = srcrank_perm[e];
            uint2 araw = *(const uint2*)(attr_p + (size_t)e * E_IN + qi);
            uint4 kraw = *(const uint4*)(kv_in + (size_t)s_ * 512 + lane * 8);
            float2 a01 = __half22float2(*(__half2*)&araw.x);
            float2 a23 = __half22float2(*(__half2*)&araw.y);
            float2 k01 = __half22float2(*(__half2*)&kraw.x);
            float2 k23 = __half22float2(*(__half2*)&kraw.y);
            float2 v01 = __half22float2(*(__half2*)&kraw.z);
            float2 v23 = __half22float2(*(__half2*)&kraw.w);
            float rr = q01.x * k01.x + q01.y * k01.y + q23.x * k23.x + q23.y * k23.y
                     + w01.x * a01.x + w01.y * a01.y + w23.x * a23.x + w23.y * a23.y;
            rr += __shfl_xor(rr, 1);
            rr += __shfl_xor(rr, 2);
            rr += __shfl_xor(rr, 4);
            rr += __shfl_xor(rr, 8);
            float ex = __expf((rr + qbh) * 0.125f);
            nv.x += ex * v01.x; nv.y += ex * v01.y; nv.z += ex * v23.x; nv.w += ex * v23.y;
            ne.x += ex * a01.x; ne.y += ex * a01.y; ne.z += ex * a23.x; ne.w += ex * a23.y;
            dsum += ex;
        }
        float rc = 1.f / (dsum + 1e-16f);
        half4 nep = {(_Float16)(ne.x * rc), (_Float16)(ne.y * rc),
                     (_Float16)(ne.z * rc), (_Float16)(ne.w * rc)};
        half4 nvp = {(_Float16)(nv.x * rc), (_Float16)(nv.y * rc),
                     (_Float16)(nv.z * rc), (_Float16)(nv.w * rc)};
        *(half4*)&ea16[m][lane * 4] = nep;     // k = head*64 + i*4 (+j)
        *(half4*)&nvs[m][lane * 4] = nvp;
        if (mrow == 0) ffs[m * 4 + head] = dsum * rc;
    }
    __syncthreads();
    // ---- phase 2a: edge-part GEMM  ea_scaled[8x256] @ Wcat[256x64] (waves 0..3) ----
    if (wave < 4) {
        int cb = wave * 16;
        f32x4 acc = {0.f, 0.f, 0.f, 0.f};
#pragma unroll
        for (int kk = 0; kk < 8; kk++) {
            half8 af = *(const half8*)&ea16[mrow][kk * 32 + quad * 8];
            half8 bf = *(const half8*)(Wcat16 + (size_t)(cb + mrow) * 256 + kk * 32 + quad * 8);
            acc = __builtin_amdgcn_mfma_f32_16x16x32_f16(af, bf, acc, 0, 0, 0);
        }
        if (quad < 2) {
#pragma unroll
            for (int reg = 0; reg < 4; reg++)
                hnew[quad * 4 + reg][cb + mrow] = acc[reg];
        }
    }
    __syncthreads();
    // ---- phase 2b: reduce + skip + residual; write h (512 = 8 nodes x 64 ch) ----
    {
        int m = t >> 6, c = t & 63;
        float s = hnew[m][c];
#pragma unroll
        for (int hh = 0; hh < 4; hh++)
            s += (float)nvs[m][hh * 64 + c] + ffs[m * 4 + hh] * bsh[hh * 64 + c];
        s *= 0.25f;
        s += skip[(base + m) * HID + c];
        if (add_res) s += hg[(base + m) * HID + c];
        if (!last) hg[(base + m) * HID + c] = s;
        hnew[m][c] = s;
    }
    __syncthreads();
    // ---- phase 3: LN + relu (8 rows, one per wave) ----
    {
        int m = wave;
        float val = hnew[m][lane];
        float mu = val;
        for (int o = 32; o > 0; o >>= 1) mu += __shfl_xor(mu, o);
        mu *= (1.f / 64.f);
        float d = val - mu;
        float var = d * d;
        for (int o = 32; o > 0; o >>= 1) var += __shfl_xor(var, o);
        var *= (1.f / 64.f);
        val = fmaxf(d * rsqrtf(var + 1e-5f) * g[lane] + be[lane], 0.f);
        if (last) hnew[m][lane] = val;
        else      zs[m][lane] = (_Float16)val;
    }
    __syncthreads();
    if (last) {
        // linear head: 8 nodes x 32 cols = 256 threads
        if (t < 256) {
            int m = t >> 5, col = t & 31;
            float a = linb[col];
            for (int i = 0; i < HID; i++) a += hnew[m][i] * linW[i * OUT_DIM + col];
            out[nord[m] * OUT_DIM + col] = a;
        }
        return;
    }
    // ---- phase 4: qb for next layer (32 pairs x 16 threads) ----
    {
        int p = t >> 4, s16 = t & 15;
        int m = p >> 2, h4 = p & 3;
        float a = 0.f;
        for (int i = s16 * 4; i < s16 * 4 + 4; i++)
            a += (float)zs[m][i] * wqb[i * NH + h4];
        a += __shfl_xor(a, 1);
        a += __shfl_xor(a, 2);
        a += __shfl_xor(a, 4);
        a += __shfl_xor(a, 8);
        if (s16 == 0) qb[(base + m) * NH + h4] = a + bqb[h4];
    }
    // ---- phase 5: z @ W16T (swapped); 68 col-tiles strided over 8 waves ----
    half8 a00 = *(const half8*)&zs[mrow][quad * 8];
    half8 a01 = *(const half8*)&zs[mrow][32 + quad * 8];
    for (int tile = wave; tile < 68; tile += 8) {
        int colb = tile * 16;
        const _Float16* wrow = W16T + (size_t)(colb + mrow) * 64;
        half8 b0f = *(const half8*)(wrow + quad * 8);
        half8 b1f = *(const half8*)(wrow + 32 + quad * 8);
        f32x4 acc = {0.f, 0.f, 0.f, 0.f};
        acc = __builtin_amdgcn_mfma_f32_16x16x32_f16(b0f, a00, acc, 0, 0, 0);
        acc = __builtin_amdgcn_mfma_f32_16x16x32_f16(b1f, a01, acc, 0, 0, 0);
        if (mrow < 8) {
            float4 bi4 = *(const float4*)(biasc + colb + quad * 4);
            int wc = colb + quad * 4;
            int ra = base + mrow;
            float v0 = acc[0] + bi4.x, v1 = acc[1] + bi4.y;
            float v2 = acc[2] + bi4.z, v3 = acc[3] + bi4.w;
            if (colb >= 1024) {
                *(float4*)(skip + ra * HID + (wc - 1024)) = make_float4(v0, v1, v2, v3);
            } else {
                half4 pk = {(_Float16)v0, (_Float16)v1, (_Float16)v2, (_Float16)v3};
                if (colb < 512) *(half4*)(qqw + (size_t)ra * 512 + wc) = pk;
                else            *(half4*)(kv_out + (size_t)ra * 512 + (wc - 512)) = pk;
            }
        }
    }
}

extern "C" void kernel_launch(void* const* d_in, const int* in_sizes, int n_in,
                              void* d_out, int out_size, void* d_ws, size_t ws_size,
                              hipStream_t stream) {
    const float* x      = (const float*)d_in[0];
    const int*   ei     = (const int*)d_in[1];
    const float* eattr  = (const float*)d_in[2];
    const float* node_W = (const float*)d_in[3];
    const float* node_b = (const float*)d_in[4];
    const float* eenc_W = (const float*)d_in[5];
    const float* eenc_b = (const float*)d_in[6];
    const float* Wq     = (const float*)d_in[7];
    const float* bq     = (const float*)d_in[8];
    const float* Wk     = (const float*)d_in[9];
    const float* bk     = (const float*)d_in[10];
    const float* Wv     = (const float*)d_in[11];
    const float* bv     = (const float*)d_in[12];
    const float* We     = (const float*)d_in[13];
    const float* Wskip  = (const float*)d_in[14];
    const float* bskip  = (const float*)d_in[15];
    const float* ln_g   = (const float*)d_in[16];
    const float* ln_b   = (const float*)d_in[17];
    const float* lin_W  = (const float*)d_in[18];
    const float* lin_b  = (const float*)d_in[19];
    float* out = (float*)d_out;

    const int* src = ei;            // edge_index[0]
    const int* dst = ei + N_EDGES;  // edge_index[1]

    float* ws = (float*)d_ws;
    __half* attr_p = (__half*)ws; ws += (size_t)N_EDGES * E_IN / 2;
    float* h    = ws; ws += N_NODES * HID;                       // rank-indexed
    _Float16* qqw = (_Float16*)ws; ws += (size_t)N_NODES * HC;   // packed q|qw f16
    _Float16* kvA = (_Float16*)ws; ws += (size_t)N_NODES * HC;   // packed k|v f16
    _Float16* kvB = (_Float16*)ws; ws += (size_t)N_NODES * HC;
    float* skip = ws; ws += N_NODES * HID;
    float* qb   = ws; ws += N_NODES * NH;
    float* Wqe2 = ws; ws += (size_t)L_LAYERS * HID * HC;
    float* bqe2 = ws; ws += L_LAYERS * HC;
    float* wqb  = ws; ws += L_LAYERS * HID * NH;
    float* bqb  = ws; ws += L_LAYERS * NH;
    _Float16* Wcat16 = (_Float16*)ws; ws += (size_t)L_LAYERS * 64 * 256 / 2;
    float* beE  = ws; ws += L_LAYERS * HC;
    _Float16* W16T = (_Float16*)ws; ws += (size_t)L_LAYERS * WCOLS * HID / 2;
    float* biasc = ws; ws += L_LAYERS * WCOLS;
    _Float16* W0T = (_Float16*)ws; ws += HID * F_IN / 2;
    float* b0  = ws; ws += HID;
    int* ip = (int*)ws;
    int* hist         = ip; ip += N_NODES;
    int* node_order   = ip; ip += N_NODES;
    int* rank_of      = ip; ip += N_NODES;
    int* deg_rank     = ip; ip += N_NODES;
    int* new_rp       = ip; ip += N_NODES + 4;
    int* cursor2      = ip; ip += N_NODES;
    int* srcrank_perm = ip; ip += N_EDGES;
    int* eid_of       = ip; ip += N_EDGES;

    hipMemsetAsync(hist, 0, N_NODES * sizeof(int), stream);
    hist_dst<<<(N_EDGES + 255) / 256, 256, 0, stream>>>(dst, hist);
    build_order<<<1, 1024, 0, stream>>>(hist, node_order, rank_of, deg_rank,
                                        new_rp, cursor2);

    make_wqeA<<<L_LAYERS * HID, 256, 0, stream>>>(Wq, bq, We, eenc_W, eenc_b,
                                                  Wqe2, bqe2, wqb, bqb);
    make_wcat<<<L_LAYERS * 64, 256, 0, stream>>>(eenc_W, eenc_b, We, Wcat16, beE);
    make_w16<<<L_LAYERS * 272, 256, 0, stream>>>(Wq, Wk, Wv, Wqe2, Wskip,
                                                 bq, bk, bv, bqe2, bskip,
                                                 W16T, biasc);
    make_w0<<<HID / 2, 256, 0, stream>>>(node_W, node_b, W0T, b0);

    compute_pos<<<(N_EDGES + 255) / 256, 256, 0, stream>>>(src, dst, rank_of, cursor2,
                                                           eid_of, srcrank_perm);
    permute_attr<<<N_EDGES / 16, 256, 0, stream>>>(eid_of, eattr, attr_p);

    node_pre0<<<N_NODES / 32, 256, 0, stream>>>(
        x, node_order, W0T, b0, W16T, biasc, wqb, bqb, qqw, kvA, skip, qb);

    for (int l = 0; l < L_LAYERS; l++) {
        const _Float16* kin = (l & 1) ? kvB : kvA;
        _Float16* kout = (l & 1) ? kvA : kvB;
        int last = (l == L_LAYERS - 1);
        int lnext = last ? 0 : (l + 1);
        layer_step<<<N_NODES / 8, 512, 0, stream>>>(
            new_rp, srcrank_perm, attr_p, (const __half*)kin,
            qqw, qb, skip, h,
            Wcat16 + (size_t)l * 64 * 256, beE + l * HC,
            (l > 0) ? 1 : 0,
            W16T + (size_t)lnext * WCOLS * HID, biasc + lnext * WCOLS,
            wqb + lnext * HID * NH, bqb + lnext * NH,
            last ? ln_g : (ln_g + (l + 1) * HID),
            last ? ln_b : (ln_b + (l + 1) * HID),
            kout, last, node_order, lin_W, lin_b, out);
    }
}

// Round 13
// 671.961 us; speedup vs baseline: 1.1808x; 1.1808x over previous
//
#include <hip/hip_runtime.h>
#include <hip/hip_fp16.h>
#include <math.h>

#define N_NODES 20000
#define N_EDGES 320000
#define F_IN    128
#define E_IN    64
#define HID     64
#define NH      4
#define CH      64
#define HC      256   // NH*CH
#define L_LAYERS 4
#define OUT_DIM 32
#define WCOLS   1088  // packed col space: 512 qqw | 512 kv | 64 skip

typedef _Float16 half8 __attribute__((ext_vector_type(8)));
typedef _Float16 half4 __attribute__((ext_vector_type(4)));
typedef float f32x4 __attribute__((ext_vector_type(4)));

// ---------------- CSR build ----------------
__global__ __launch_bounds__(256) void hist_dst(const int* __restrict__ dst,
                                                int* __restrict__ hist) {
    int e = blockIdx.x * 256 + threadIdx.x;
    if (e < N_EDGES) atomicAdd(&hist[dst[e]], 1);
}

// one block, 1024 threads: degree-descending rank + CSR row pointers
__global__ __launch_bounds__(1024) void build_order(const int* __restrict__ hist,
                                                    int* __restrict__ node_order,
                                                    int* __restrict__ rank_of,
                                                    int* __restrict__ deg_rank,
                                                    int* __restrict__ new_rp,
                                                    int* __restrict__ cursor2) {
    __shared__ int bins[256];
    __shared__ int curb[256];
    __shared__ int sums[1024];
    int t = threadIdx.x;
    if (t < 256) bins[t] = 0;
    __syncthreads();
    for (int n = t; n < N_NODES; n += 1024) {
        int d = hist[n]; if (d > 255) d = 255;
        atomicAdd(&bins[d], 1);
    }
    __syncthreads();
    if (t < 256) {
        int acc = 0;
        for (int b = t + 1; b < 256; b++) acc += bins[b];
        curb[t] = acc;
    }
    __syncthreads();
    for (int n = t; n < N_NODES; n += 1024) {
        int d = hist[n];
        int b = d > 255 ? 255 : d;
        int r = atomicAdd(&curb[b], 1);
        node_order[r] = n;
        rank_of[n] = r;
        deg_rank[r] = d;
    }
    __syncthreads();
    const int CHUNK = 20;  // 1024*20 >= 20000
    int base = t * CHUNK;
    int local[CHUNK];
    int s = 0;
    for (int i = 0; i < CHUNK; i++) {
        int idx = base + i;
        int vv = (idx < N_NODES) ? deg_rank[idx] : 0;
        local[i] = s;
        s += vv;
    }
    sums[t] = s;
    __syncthreads();
    for (int off = 1; off < 1024; off <<= 1) {
        int v = (t >= off) ? sums[t - off] : 0;
        __syncthreads();
        sums[t] += v;
        __syncthreads();
    }
    int excl = (t == 0) ? 0 : sums[t - 1];
    for (int i = 0; i < CHUNK; i++) {
        int idx = base + i;
        if (idx < N_NODES) {
            int p = excl + local[i];
            new_rp[idx] = p;
            cursor2[idx] = p;
        }
    }
    if (t == 1023) new_rp[N_NODES] = sums[1023];
}

// phase A: positions only
__global__ __launch_bounds__(256) void compute_pos(const int* __restrict__ src,
                                                   const int* __restrict__ dst,
                                                   const int* __restrict__ rank_of,
                                                   int* __restrict__ cursor2,
                                                   int* __restrict__ eid_of,
                                                   int* __restrict__ srcrank_perm) {
    int e = blockIdx.x * 256 + threadIdx.x;
    if (e >= N_EDGES) return;
    int r = rank_of[dst[e]];
    int pos = atomicAdd(&cursor2[r], 1);
    eid_of[pos] = e;
    srcrank_perm[pos] = rank_of[src[e]];
}

// phase B: gather-form attr permute + fp16 convert
__global__ __launch_bounds__(256) void permute_attr(const int* __restrict__ eid_of,
                                                    const float* __restrict__ eattr,
                                                    __half* __restrict__ attr_p) {
    int t = threadIdx.x;
    int wave = t >> 6, lane = t & 63;
    int p = blockIdx.x * 16 + wave * 4 + (lane >> 4);
    if (p >= N_EDGES) return;
    int e = eid_of[p];
    int qi = (lane & 15) * 4;
    float4 a = *(const float4*)(eattr + (size_t)e * E_IN + qi);
    __half2 h0 = __floats2half2_rn(a.x, a.y);
    __half2 h1 = __floats2half2_rn(a.z, a.w);
    uint2 packed;
    packed.x = *(unsigned int*)&h0;
    packed.y = *(unsigned int*)&h1;
    *(uint2*)(attr_p + (size_t)p * E_IN + qi) = packed;
}

// ---------------- per-layer constants ----------------
// fused: Wqe (LDS) -> Wqe2 / bqe2 / wqb / bqb
__global__ __launch_bounds__(256) void make_wqeA(const float* __restrict__ Wq,
                                                 const float* __restrict__ bq,
                                                 const float* __restrict__ We,
                                                 const float* __restrict__ eW,
                                                 const float* __restrict__ eb,
                                                 float* __restrict__ Wqe2,
                                                 float* __restrict__ bqe2,
                                                 float* __restrict__ wqb,
                                                 float* __restrict__ bqb) {
    int l = blockIdx.x / HID, i = blockIdx.x % HID;
    int t = threadIdx.x;
    int h = t >> 6, j = t & 63;
    __shared__ float wrow[256];
    __shared__ float brow[256];
    const float* WqL = Wq + (size_t)l * HID * HC;
    const float* WeL = We + (size_t)l * HID * HC;
    float acc = 0.f;
    for (int c = 0; c < CH; c++)
        acc += WqL[i * HC + h * CH + c] * WeL[j * HC + h * CH + c];
    wrow[t] = acc;
    if (i == 0) {
        const float* bqL = bq + l * HC;
        float ab = 0.f;
        for (int c = 0; c < CH; c++)
            ab += bqL[h * CH + c] * WeL[j * HC + h * CH + c];
        brow[t] = ab;
    }
    __syncthreads();
    int h2 = t >> 6, m = t & 63;
    float a2 = 0.f;
    for (int jj = 0; jj < HID; jj++) a2 += wrow[h2 * 64 + jj] * eW[m * HID + jj];
    Wqe2[(size_t)l * HID * HC + i * HC + t] = a2;
    if (m == 0) {
        float aw = 0.f;
        for (int jj = 0; jj < HID; jj++) aw += wrow[h2 * 64 + jj] * eb[jj];
        wqb[l * HID * NH + i * NH + h2] = aw;
    }
    if (i == 0) {
        float ab2 = 0.f;
        for (int jj = 0; jj < HID; jj++) ab2 += brow[h2 * 64 + jj] * eW[m * HID + jj];
        bqe2[l * HC + t] = ab2;
        if (m == 0) {
            float bb = 0.f;
            for (int jj = 0; jj < HID; jj++) bb += brow[h2 * 64 + jj] * eb[jj];
            bqb[l * NH + h2] = bb;
        }
    }
}

// Wcat16[l][c(64)][k=h*64+m (256)] = f16( WeE[m][h*64+c] );  beE fp32
__global__ __launch_bounds__(256) void make_wcat(const float* __restrict__ eW,
                                                 const float* __restrict__ eb,
                                                 const float* __restrict__ We,
                                                 _Float16* __restrict__ Wcat16,
                                                 float* __restrict__ beE) {
    int l = blockIdx.x / 64, c = blockIdx.x % 64;
    int t = threadIdx.x;
    __shared__ float sh[4][64];    // sh[h][j] = We[j][h*64+c]
    {
        int j = t & 63, h = t >> 6;
        sh[h][j] = We[(size_t)l * HID * HC + j * HC + h * 64 + c];
    }
    __syncthreads();
    int h = t >> 6, m = t & 63;
    float acc = 0.f;
    for (int j = 0; j < HID; j++) acc += eW[m * HID + j] * sh[h][j];
    Wcat16[((size_t)l * 64 + c) * 256 + t] = (_Float16)acc;
    if (t < 4) {
        float a = 0.f;
        for (int j = 0; j < HID; j++) a += eb[j] * sh[t][j];
        beE[l * HC + t * 64 + c] = a;
    }
}

// W16T: columns pre-permuted into the PACKED output order (see round 9)
__global__ __launch_bounds__(256) void make_w16(
        const float* __restrict__ Wq, const float* __restrict__ Wk,
        const float* __restrict__ Wv, const float* __restrict__ Wqe2,
        const float* __restrict__ Wsk,
        const float* __restrict__ bq, const float* __restrict__ bk,
        const float* __restrict__ bv, const float* __restrict__ bqe2,
        const float* __restrict__ bsk,
        _Float16* __restrict__ W16T, float* __restrict__ biasc) {
    int l = blockIdx.x / 272;
    int cg = blockIdx.x % 272;
    int col = cg * 4 + (threadIdx.x >> 6);
    int i = threadIdx.x & 63;
    float w, b;
    if (col < 512) {
        int c = (col >> 3) * 4 + (col & 3);
        if ((col >> 2) & 1) { w = Wqe2[(size_t)l*HID*HC + i*HC + c]; b = bqe2[l*HC + c]; }
        else                { w = Wq[(size_t)l*HID*HC + i*HC + c];   b = bq[l*HC + c]; }
    } else if (col < 1024) {
        int cc = col - 512;
        int c = (cc >> 3) * 4 + (cc & 3);
        if ((cc >> 2) & 1) { w = Wv[(size_t)l*HID*HC + i*HC + c]; b = bv[l*HC + c]; }
        else               { w = Wk[(size_t)l*HID*HC + i*HC + c]; b = bk[l*HC + c]; }
    } else {
        int c = col - 1024;
        w = Wsk[(size_t)l*HID*HID + i*HID + c];  b = bsk[l*HID + c];
    }
    W16T[((size_t)l * WCOLS + col) * 64 + i] = (_Float16)w;
    if (i == 0) biasc[l * WCOLS + col] = b;
}

// W0T[col][i] = f16 node_W[i][col]  (64 cols, K=128); b0 fp32
__global__ __launch_bounds__(256) void make_w0(const float* __restrict__ nW,
                                               const float* __restrict__ nb,
                                               _Float16* __restrict__ W0T,
                                               float* __restrict__ b0) {
    int col = blockIdx.x * 2 + (threadIdx.x >> 7);
    int i = threadIdx.x & 127;
    W0T[col * F_IN + i] = (_Float16)nW[i * HID + col];
    if (i == 0) b0[col] = nb[col];
}

// ---------------- layer-0: fused node-encoder + pre-pass (32 nodes/block) ----------------
__global__ __launch_bounds__(256) void node_pre0(const float* __restrict__ x,
        const int* __restrict__ node_order,
        const _Float16* __restrict__ W0T, const float* __restrict__ b0,
        const _Float16* __restrict__ W16T, const float* __restrict__ biasc,
        const float* __restrict__ wqb, const float* __restrict__ bqb,
        _Float16* __restrict__ qqw, _Float16* __restrict__ kv,
        float* __restrict__ skip, float* __restrict__ qb) {
    int t = threadIdx.x;
    int wave = t >> 6, lane = t & 63;
    int quad = lane >> 4, mrow = lane & 15;
    int base = blockIdx.x * 32;
    __shared__ _Float16 xs[32][136];
    __shared__ _Float16 zs[32][72];
    __shared__ int nord[32];
    if (t < 32) nord[t] = node_order[base + t];
    __syncthreads();
    for (int it = 0; it < 4; it++) {
        int idx = it * 256 + t;          // 1024 float4 = 32 rows x 32
        int m = idx >> 5, c4 = idx & 31;
        float4 a = *(const float4*)(x + (size_t)nord[m] * F_IN + c4 * 4);
        _Float16* d = &xs[m][c4 * 4];
        d[0] = (_Float16)a.x; d[1] = (_Float16)a.y;
        d[2] = (_Float16)a.z; d[3] = (_Float16)a.w;
    }
    __syncthreads();
    // h0 = x @ node_W + node_b, SWAPPED: D[wcol][node] -> 8B LDS stores
    {
        int colb = wave * 16;
        const _Float16* w0row = W0T + (size_t)(colb + mrow) * F_IN;
        f32x4 acc0 = {0.f, 0.f, 0.f, 0.f};
        f32x4 acc1 = {0.f, 0.f, 0.f, 0.f};
#pragma unroll
        for (int kk = 0; kk < 4; kk++) {
            half8 wfrag = *(const half8*)(w0row + kk * 32 + quad * 8);
            half8 xf0 = *(const half8*)&xs[mrow][kk * 32 + quad * 8];
            half8 xf1 = *(const half8*)&xs[16 + mrow][kk * 32 + quad * 8];
            acc0 = __builtin_amdgcn_mfma_f32_16x16x32_f16(wfrag, xf0, acc0, 0, 0, 0);
            acc1 = __builtin_amdgcn_mfma_f32_16x16x32_f16(wfrag, xf1, acc1, 0, 0, 0);
        }
        float4 bb = *(const float4*)(b0 + colb + quad * 4);
        half4 h0v = {(_Float16)(acc0[0] + bb.x), (_Float16)(acc0[1] + bb.y),
                     (_Float16)(acc0[2] + bb.z), (_Float16)(acc0[3] + bb.w)};
        half4 h1v = {(_Float16)(acc1[0] + bb.x), (_Float16)(acc1[1] + bb.y),
                     (_Float16)(acc1[2] + bb.z), (_Float16)(acc1[3] + bb.w)};
        *(half4*)&zs[mrow][colb + quad * 4] = h0v;
        *(half4*)&zs[16 + mrow][colb + quad * 4] = h1v;
    }
    __syncthreads();
    // qb: 128 (m,h4) pairs x 2 threads
    {
        int p = t >> 1, s4 = t & 1;
        int m = p >> 2, h4 = p & 3;
        float a = 0.f;
        for (int i = s4 * 32; i < s4 * 32 + 32; i++)
            a += (float)zs[m][i] * wqb[i * NH + h4];
        a += __shfl_xor(a, 1);
        if (s4 == 0) qb[(base + m) * NH + h4] = a + bqb[h4];
    }
    half8 a00 = *(const half8*)&zs[mrow][quad * 8];
    half8 a01 = *(const half8*)&zs[mrow][32 + quad * 8];
    half8 a10 = *(const half8*)&zs[16 + mrow][quad * 8];
    half8 a11 = *(const half8*)&zs[16 + mrow][32 + quad * 8];
    int colwave = wave * 272;
    for (int tile = 0; tile < 17; tile++) {
        int colb = colwave + tile * 16;
        const _Float16* wrow = W16T + (size_t)(colb + mrow) * 64;
        half8 b0f = *(const half8*)(wrow + quad * 8);
        half8 b1f = *(const half8*)(wrow + 32 + quad * 8);
        f32x4 acc0 = {0.f, 0.f, 0.f, 0.f};
        f32x4 acc1 = {0.f, 0.f, 0.f, 0.f};
        acc0 = __builtin_amdgcn_mfma_f32_16x16x32_f16(b0f, a00, acc0, 0, 0, 0);
        acc0 = __builtin_amdgcn_mfma_f32_16x16x32_f16(b1f, a01, acc0, 0, 0, 0);
        acc1 = __builtin_amdgcn_mfma_f32_16x16x32_f16(b0f, a10, acc1, 0, 0, 0);
        acc1 = __builtin_amdgcn_mfma_f32_16x16x32_f16(b1f, a11, acc1, 0, 0, 0);
        float4 bi4 = *(const float4*)(biasc + colb + quad * 4);
        int wc = colb + quad * 4;
        int ra = base + mrow, rb = ra + 16;
        float v00 = acc0[0] + bi4.x, v01 = acc0[1] + bi4.y;
        float v02 = acc0[2] + bi4.z, v03 = acc0[3] + bi4.w;
        float v10 = acc1[0] + bi4.x, v11 = acc1[1] + bi4.y;
        float v12 = acc1[2] + bi4.z, v13 = acc1[3] + bi4.w;
        if (colb >= 1024) {
            *(float4*)(skip + ra * HID + (wc - 1024)) = make_float4(v00, v01, v02, v03);
            *(float4*)(skip + rb * HID + (wc - 1024)) = make_float4(v10, v11, v12, v13);
        } else {
            half4 p0 = {(_Float16)v00, (_Float16)v01, (_Float16)v02, (_Float16)v03};
            half4 p1 = {(_Float16)v10, (_Float16)v11, (_Float16)v12, (_Float16)v13};
            if (colb < 512) {
                *(half4*)(qqw + (size_t)ra * 512 + wc) = p0;
                *(half4*)(qqw + (size_t)rb * 512 + wc) = p1;
            } else {
                *(half4*)(kv + (size_t)ra * 512 + (wc - 512)) = p0;
                *(half4*)(kv + (size_t)rb * 512 + (wc - 512)) = p1;
            }
        }
    }
}

// ---------------- per-layer edge gather: 1 wave = 1 rank; quarter-wave = 1 head ----
__global__ __launch_bounds__(256) void gather_edges(
        const int* __restrict__ new_rp,
        const int* __restrict__ srcrank_perm, const __half* __restrict__ attr_p,
        const __half* __restrict__ kv,
        const float* __restrict__ qb,
        const __half* qqw,            // aliases numv — no restrict
        float* numv, __half* __restrict__ numea16,
        float* __restrict__ den) {
    int wave = threadIdx.x >> 6;
    int lane = threadIdx.x & 63;
    int r = blockIdx.x * 4 + wave;
    if (r >= N_NODES) return;
    int e0 = new_rp[r], e1 = new_rp[r + 1];
    int qi = (lane & 15) * 4;
    int head = lane >> 4;
    uint4 qr = *(const uint4*)(qqw + (size_t)r * 512 + lane * 8);
    float2 q01 = __half22float2(*(__half2*)&qr.x);
    float2 q23 = __half22float2(*(__half2*)&qr.y);
    float2 w01 = __half22float2(*(__half2*)&qr.z);
    float2 w23 = __half22float2(*(__half2*)&qr.w);
    float qbh = qb[r * NH + head];
    float4 nv = make_float4(0.f, 0.f, 0.f, 0.f);
    float4 ne = make_float4(0.f, 0.f, 0.f, 0.f);
    float dsum = 0.f;
#pragma unroll 4
    for (int e = e0; e < e1; e++) {
        int s_ = srcrank_perm[e];
        uint2 araw = *(const uint2*)(attr_p + (size_t)e * E_IN + qi);
        uint4 kraw = *(const uint4*)(kv + (size_t)s_ * (2 * HC) + lane * 8);
        float2 a01 = __half22float2(*(__half2*)&araw.x);
        float2 a23 = __half22float2(*(__half2*)&araw.y);
        float2 k01 = __half22float2(*(__half2*)&kraw.x);
        float2 k23 = __half22float2(*(__half2*)&kraw.y);
        float2 v01 = __half22float2(*(__half2*)&kraw.z);
        float2 v23 = __half22float2(*(__half2*)&kraw.w);
        float rr = q01.x * k01.x + q01.y * k01.y + q23.x * k23.x + q23.y * k23.y
                 + w01.x * a01.x + w01.y * a01.y + w23.x * a23.x + w23.y * a23.y;
        rr += __shfl_xor(rr, 1);
        rr += __shfl_xor(rr, 2);
        rr += __shfl_xor(rr, 4);
        rr += __shfl_xor(rr, 8);
        float ex = __expf((rr + qbh) * 0.125f);
        nv.x += ex * v01.x; nv.y += ex * v01.y; nv.z += ex * v23.x; nv.w += ex * v23.y;
        ne.x += ex * a01.x; ne.y += ex * a01.y; ne.z += ex * a23.x; ne.w += ex * a23.y;
        dsum += ex;
    }
    *(float4*)(numv + (size_t)r * HC + lane * 4) = nv;     // overwrites qqw row (dead)
    __half2 n01 = __floats2half2_rn(ne.x, ne.y);
    __half2 n23 = __floats2half2_rn(ne.z, ne.w);
    uint2 np;
    np.x = *(unsigned int*)&n01;
    np.y = *(unsigned int*)&n23;
    *(uint2*)(numea16 + (size_t)r * HC + lane * 4) = np;
    if ((lane & 15) == 0) den[r * NH + head] = dsum;
}

// ---------------- fused node_post(l) + node_pre(l+1): 16 nodes/block ----------------
// h lives in RANK space.
__global__ __launch_bounds__(256) void node_mid(
        const float* numv,                    // aliases qqw — no restrict
        const __half* __restrict__ numea16,
        const float* __restrict__ den_g,
        float* skip,                          // read layer l, write layer l+1
        float* __restrict__ hg,               // rank-indexed
        const _Float16* __restrict__ Wcat16,  // [64 c][256 k] layer l
        const float* __restrict__ beE,        // [256]         layer l
        int add_res,
        const _Float16* __restrict__ W16T,    // [1088][64] layer l+1 (packed cols)
        const float* __restrict__ biasc,
        const float* __restrict__ wqb, const float* __restrict__ bqb,
        const float* __restrict__ g, const float* __restrict__ be,
        _Float16* qqw, _Float16* __restrict__ kv,
        float* __restrict__ qb) {
    int t = threadIdx.x;
    int wave = t >> 6, lane = t & 63;
    int quad = lane >> 4, mrow = lane & 15;
    int base = blockIdx.x * 16;
    __shared__ _Float16 ea16[16][264];
    __shared__ float hnew[16][64];
    __shared__ _Float16 zs[16][72];
    __shared__ float bsh[256];
    __shared__ float rr_[64];   // 1/(den+eps)
    __shared__ float ff_[64];   // den/(den+eps)
    if (t < 64) {
        float dd = den_g[base * 4 + t];
        float rc = 1.f / (dd + 1e-16f);
        rr_[t] = rc;
        ff_[t] = dd * rc;
    }
    bsh[t] = beE[t];
    __syncthreads();
    // stage numea scaled by 1/(den_h+eps), f16
    for (int it = 0; it < 2; it++) {
        int idx = it * 256 + t;        // 512 chunks of 8 halfs = 16 rows x 32
        int m = idx >> 5, c8 = idx & 31;
        float rc = rr_[m * 4 + (c8 >> 3)];
        uint4 raw = *(const uint4*)(numea16 + (size_t)(base + m) * HC + c8 * 8);
        __half2* hp = (__half2*)&raw;
#pragma unroll
        for (int i = 0; i < 4; i++) {
            float2 f = __half22float2(hp[i]);
            hp[i] = __floats2half2_rn(f.x * rc, f.y * rc);
        }
        *(uint4*)&ea16[m][c8 * 8] = raw;
    }
    __syncthreads();
    // phase 1: ONE K=256 GEMM  ea_scaled[16x256] @ Wcat[256x64] -> hnew raw
    {
        int cb = wave * 16;
        f32x4 acc = {0.f, 0.f, 0.f, 0.f};
#pragma unroll
        for (int kk = 0; kk < 8; kk++) {
            half8 af = *(const half8*)&ea16[mrow][kk * 32 + quad * 8];
            half8 bf = *(const half8*)(Wcat16 + (size_t)(cb + mrow) * 256 + kk * 32 + quad * 8);
            acc = __builtin_amdgcn_mfma_f32_16x16x32_f16(af, bf, acc, 0, 0, 0);
        }
#pragma unroll
        for (int reg = 0; reg < 4; reg++)
            hnew[quad * 4 + reg][cb + mrow] = acc[reg];
    }
    __syncthreads();
    // reduce: + per-head numv/den + den*beE/den, x0.25, +skip (+res); write h
    for (int it = 0; it < 4; it++) {
        int idx = it * 256 + t;
        int m = idx >> 6, c = idx & 63;
        float s = hnew[m][c];
#pragma unroll
        for (int hh = 0; hh < 4; hh++)
            s += numv[(size_t)(base + m) * HC + hh * 64 + c] * rr_[m * 4 + hh]
               + ff_[m * 4 + hh] * bsh[hh * 64 + c];
        s *= 0.25f;
        s += skip[(base + m) * HID + c];
        if (add_res) s += hg[(base + m) * HID + c];
        hg[(base + m) * HID + c] = s;
        hnew[m][c] = s;
    }
    __syncthreads();
    // LN + relu -> zs f16
    for (int it = 0; it < 4; it++) {
        int m = it * 4 + wave;
        float val = hnew[m][lane];
        float mu = val;
        for (int o = 32; o > 0; o >>= 1) mu += __shfl_xor(mu, o);
        mu *= (1.f / 64.f);
        float d = val - mu;
        float var = d * d;
        for (int o = 32; o > 0; o >>= 1) var += __shfl_xor(var, o);
        var *= (1.f / 64.f);
        val = fmaxf(d * rsqrtf(var + 1e-5f) * g[lane] + be[lane], 0.f);
        zs[m][lane] = (_Float16)val;
    }
    __syncthreads();
    // qb: 64 (m,h4) pairs x 4 threads
    {
        int p = t >> 2, s4 = t & 3;
        int m = p >> 2, h4 = p & 3;
        float a = 0.f;
        for (int i = s4 * 16; i < s4 * 16 + 16; i++)
            a += (float)zs[m][i] * wqb[i * NH + h4];
        a += __shfl_xor(a, 1);
        a += __shfl_xor(a, 2);
        if (s4 == 0) qb[(base + m) * NH + h4] = a + bqb[h4];
    }
    // phase 2: z @ W16T, SWAPPED -> 8B packed stores
    half8 a00 = *(const half8*)&zs[mrow][quad * 8];
    half8 a01 = *(const half8*)&zs[mrow][32 + quad * 8];
    int colwave = wave * 272;
    for (int tile = 0; tile < 17; tile++) {
        int colb = colwave + tile * 16;
        const _Float16* wrow = W16T + (size_t)(colb + mrow) * 64;
        half8 b0f = *(const half8*)(wrow + quad * 8);
        half8 b1f = *(const half8*)(wrow + 32 + quad * 8);
        f32x4 acc = {0.f, 0.f, 0.f, 0.f};
        acc = __builtin_amdgcn_mfma_f32_16x16x32_f16(b0f, a00, acc, 0, 0, 0);
        acc = __builtin_amdgcn_mfma_f32_16x16x32_f16(b1f, a01, acc, 0, 0, 0);
        float4 bi4 = *(const float4*)(biasc + colb + quad * 4);
        int wc = colb + quad * 4;
        int ra = base + mrow;
        float v0 = acc[0] + bi4.x, v1 = acc[1] + bi4.y;
        float v2 = acc[2] + bi4.z, v3 = acc[3] + bi4.w;
        if (colb >= 1024) {
            *(float4*)(skip + ra * HID + (wc - 1024)) = make_float4(v0, v1, v2, v3);
        } else {
            half4 pk = {(_Float16)v0, (_Float16)v1, (_Float16)v2, (_Float16)v3};
            if (colb < 512) *(half4*)(qqw + (size_t)ra * 512 + wc) = pk;
            else            *(half4*)(kv + (size_t)ra * 512 + (wc - 512)) = pk;
        }
    }
}

// ---------------- fused node_post(3) + final LN + linear head ----------------
__global__ __launch_bounds__(256) void node_fin(
        const int* __restrict__ node_order,
        const float* __restrict__ numv,
        const __half* __restrict__ numea16,
        const float* __restrict__ den_g,
        const float* __restrict__ skip,
        const float* __restrict__ hg,         // rank-indexed
        const _Float16* __restrict__ Wcat16, const float* __restrict__ beE,
        const float* __restrict__ g, const float* __restrict__ be,   // ln_g[0]
        const float* __restrict__ linW, const float* __restrict__ linb,
        float* __restrict__ out) {
    int t = threadIdx.x;
    int wave = t >> 6, lane = t & 63;
    int quad = lane >> 4, mrow = lane & 15;
    int base = blockIdx.x * 16;
    __shared__ _Float16 ea16[16][264];
    __shared__ float hnew[16][64];
    __shared__ float bsh[256];
    __shared__ float rr_[64];
    __shared__ float ff_[64];
    __shared__ int nord[16];
    if (t < 16) nord[t] = node_order[base + t];
    if (t < 64) {
        float dd = den_g[base * 4 + t];
        float rc = 1.f / (dd + 1e-16f);
        rr_[t] = rc;
        ff_[t] = dd * rc;
    }
    bsh[t] = beE[t];
    __syncthreads();
    for (int it = 0; it < 2; it++) {
        int idx = it * 256 + t;
        int m = idx >> 5, c8 = idx & 31;
        float rc = rr_[m * 4 + (c8 >> 3)];
        uint4 raw = *(const uint4*)(numea16 + (size_t)(base + m) * HC + c8 * 8);
        __half2* hp = (__half2*)&raw;
#pragma unroll
        for (int i = 0; i < 4; i++) {
            float2 f = __half22float2(hp[i]);
            hp[i] = __floats2half2_rn(f.x * rc, f.y * rc);
        }
        *(uint4*)&ea16[m][c8 * 8] = raw;
    }
    __syncthreads();
    {
        int cb = wave * 16;
        f32x4 acc = {0.f, 0.f, 0.f, 0.f};
#pragma unroll
        for (int kk = 0; kk < 8; kk++) {
            half8 af = *(const half8*)&ea16[mrow][kk * 32 + quad * 8];
            half8 bf = *(const half8*)(Wcat16 + (size_t)(cb + mrow) * 256 + kk * 32 + quad * 8);
            acc = __builtin_amdgcn_mfma_f32_16x16x32_f16(af, bf, acc, 0, 0, 0);
        }
#pragma unroll
        for (int reg = 0; reg < 4; reg++)
            hnew[quad * 4 + reg][cb + mrow] = acc[reg];
    }
    __syncthreads();
    for (int it = 0; it < 4; it++) {
        int idx = it * 256 + t;
        int m = idx >> 6, c = idx & 63;
        float s = hnew[m][c];
#pragma unroll
        for (int hh = 0; hh < 4; hh++)
            s += numv[(size_t)(base + m) * HC + hh * 64 + c] * rr_[m * 4 + hh]
               + ff_[m * 4 + hh] * bsh[hh * 64 + c];
        s *= 0.25f;
        s += skip[(base + m) * HID + c] + hg[(base + m) * HID + c];
        hnew[m][c] = s;
    }
    __syncthreads();
    for (int it = 0; it < 4; it++) {
        int m = it * 4 + wave;
        float val = hnew[m][lane];
        float mu = val;
        for (int o = 32; o > 0; o >>= 1) mu += __shfl_xor(mu, o);
        mu *= (1.f / 64.f);
        float d = val - mu;
        float var = d * d;
        for (int o = 32; o > 0; o >>= 1) var += __shfl_xor(var, o);
        var *= (1.f / 64.f);
        hnew[m][lane] = fmaxf(d * rsqrtf(var + 1e-5f) * g[lane] + be[lane], 0.f);
    }
    __syncthreads();
    for (int it = 0; it < 2; it++) {
        int idx = it * 256 + t;          // 512 = 16 nodes x 32 cols
        int m = idx >> 5, col = idx & 31;
        float a = linb[col];
        for (int i = 0; i < HID; i++) a += hnew[m][i] * linW[i * OUT_DIM + col];
        out[nord[m] * OUT_DIM + col] = a;
    }
}

extern "C" void kernel_launch(void* const* d_in, const int* in_sizes, int n_in,
                              void* d_out, int out_size, void* d_ws, size_t ws_size,
                              hipStream_t stream) {
    const float* x      = (const float*)d_in[0];
    const int*   ei     = (const int*)d_in[1];
    const float* eattr  = (const float*)d_in[2];
    const float* node_W = (const float*)d_in[3];
    const float* node_b = (const float*)d_in[4];
    const float* eenc_W = (const float*)d_in[5];
    const float* eenc_b = (const float*)d_in[6];
    const float* Wq     = (const float*)d_in[7];
    const float* bq     = (const float*)d_in[8];
    const float* Wk     = (const float*)d_in[9];
    const float* bk     = (const float*)d_in[10];
    const float* Wv     = (const float*)d_in[11];
    const float* bv     = (const float*)d_in[12];
    const float* We     = (const float*)d_in[13];
    const float* Wskip  = (const float*)d_in[14];
    const float* bskip  = (const float*)d_in[15];
    const float* ln_g   = (const float*)d_in[16];
    const float* ln_b   = (const float*)d_in[17];
    const float* lin_W  = (const float*)d_in[18];
    const float* lin_b  = (const float*)d_in[19];
    float* out = (float*)d_out;

    const int* src = ei;            // edge_index[0]
    const int* dst = ei + N_EDGES;  // edge_index[1]

    float* ws = (float*)d_ws;
    __half* attr_p = (__half*)ws; ws += (size_t)N_EDGES * E_IN / 2;
    float* h    = ws; ws += N_NODES * HID;                       // rank-indexed
    _Float16* qqw = (_Float16*)ws; ws += (size_t)N_NODES * HC;   // packed q|qw -> numv
    float* numv = (float*)qqw;                                   // alias view
    __half* numea16 = (__half*)ws; ws += (size_t)N_NODES * HC / 2;
    _Float16* kv = (_Float16*)ws; ws += (size_t)N_NODES * HC;    // packed k|v f16
    float* skip = ws; ws += N_NODES * HID;
    float* den  = ws; ws += N_NODES * NH;
    float* qb   = ws; ws += N_NODES * NH;
    float* Wqe2 = ws; ws += (size_t)L_LAYERS * HID * HC;
    float* bqe2 = ws; ws += L_LAYERS * HC;
    float* wqb  = ws; ws += L_LAYERS * HID * NH;
    float* bqb  = ws; ws += L_LAYERS * NH;
    _Float16* Wcat16 = (_Float16*)ws; ws += (size_t)L_LAYERS * 64 * 256 / 2;
    float* beE  = ws; ws += L_LAYERS * HC;
    _Float16* W16T = (_Float16*)ws; ws += (size_t)L_LAYERS * WCOLS * HID / 2;
    float* biasc = ws; ws += L_LAYERS * WCOLS;
    _Float16* W0T = (_Float16*)ws; ws += HID * F_IN / 2;
    float* b0  = ws; ws += HID;
    int* ip = (int*)ws;
    int* hist         = ip; ip += N_NODES;
    int* node_order   = ip; ip += N_NODES;
    int* rank_of      = ip; ip += N_NODES;
    int* deg_rank     = ip; ip += N_NODES;
    int* new_rp       = ip; ip += N_NODES + 4;
    int* cursor2      = ip; ip += N_NODES;
    int* srcrank_perm = ip; ip += N_EDGES;
    int* eid_of       = ip; ip += N_EDGES;

    hipMemsetAsync(hist, 0, N_NODES * sizeof(int), stream);
    hist_dst<<<(N_EDGES + 255) / 256, 256, 0, stream>>>(dst, hist);
    build_order<<<1, 1024, 0, stream>>>(hist, node_order, rank_of, deg_rank,
                                        new_rp, cursor2);

    make_wqeA<<<L_LAYERS * HID, 256, 0, stream>>>(Wq, bq, We, eenc_W, eenc_b,
                                                  Wqe2, bqe2, wqb, bqb);
    make_wcat<<<L_LAYERS * 64, 256, 0, stream>>>(eenc_W, eenc_b, We, Wcat16, beE);
    make_w16<<<L_LAYERS * 272, 256, 0, stream>>>(Wq, Wk, Wv, Wqe2, Wskip,
                                                 bq, bk, bv, bqe2, bskip,
                                                 W16T, biasc);
    make_w0<<<HID / 2, 256, 0, stream>>>(node_W, node_b, W0T, b0);

    compute_pos<<<(N_EDGES + 255) / 256, 256, 0, stream>>>(src, dst, rank_of, cursor2,
                                                           eid_of, srcrank_perm);
    permute_attr<<<N_EDGES / 16, 256, 0, stream>>>(eid_of, eattr, attr_p);

    node_pre0<<<N_NODES / 32, 256, 0, stream>>>(
        x, node_order, W0T, b0, W16T, biasc, wqb, bqb, qqw, kv, skip, qb);

    for (int l = 0; l < L_LAYERS; l++) {
        gather_edges<<<(N_NODES + 3) / 4, 256, 0, stream>>>(
            new_rp, srcrank_perm, attr_p, (const __half*)kv, qb,
            (const __half*)qqw, numv, numea16, den);
        if (l < L_LAYERS - 1) {
            node_mid<<<N_NODES / 16, 256, 0, stream>>>(
                numv, numea16, den, skip, h,
                Wcat16 + (size_t)l * 64 * 256, beE + l * HC,
                (l > 0) ? 1 : 0,
                W16T + (size_t)(l + 1) * WCOLS * HID, biasc + (l + 1) * WCOLS,
                wqb + (l + 1) * HID * NH, bqb + (l + 1) * NH,
                ln_g + (l + 1) * HID, ln_b + (l + 1) * HID,
                qqw, kv, qb);
        } else {
            node_fin<<<N_NODES / 16, 256, 0, stream>>>(
                node_order, numv, numea16, den, skip, h,
                Wcat16 + (size_t)l * 64 * 256, beE + l * HC,
                ln_g, ln_b, lin_W, lin_b, out);
        }
    }
}